// Round 4
// baseline (144.711 us; speedup 1.0000x reference)
//
#include <hip/hip_runtime.h>
#include <hip/hip_bf16.h>
#include <stdint.h>

#define BATCH 8192
#define IN    1024
#define OUTD  1024
#define PBASIS 8

typedef __attribute__((ext_vector_type(8))) short bf16x8;
typedef __attribute__((ext_vector_type(4))) float floatx4;

__device__ __forceinline__ unsigned short f2bf(float f) {
    union { float f; unsigned u; } v; v.f = f;
    unsigned u = v.u;
    u += 0x7fffu + ((u >> 16) & 1u);   // RNE; inputs finite randn
    return (unsigned short)(u >> 16);
}

// Fused prep: blocks [0,4096) convert x -> bf16 (8 elem/thread);
// blocks [4096,6144) compute w_eff = bf16(sum_p coef * w) (2 elem/thread).
__global__ void prep_kernel(const float* __restrict__ x,
                            const float* __restrict__ coef,
                            const float* __restrict__ w,
                            unsigned short* __restrict__ xb,
                            unsigned short* __restrict__ weff) {
    int b = blockIdx.x;
    int tid = threadIdx.x;
    if (b < 4096) {
        int idx = b * 256 + tid;
        const float4* p = (const float4*)(x + (size_t)idx * 8);
        float4 a = p[0], c = p[1];
        uint4 o;
        o.x = (unsigned)f2bf(a.x) | ((unsigned)f2bf(a.y) << 16);
        o.y = (unsigned)f2bf(a.z) | ((unsigned)f2bf(a.w) << 16);
        o.z = (unsigned)f2bf(c.x) | ((unsigned)f2bf(c.y) << 16);
        o.w = (unsigned)f2bf(c.z) | ((unsigned)f2bf(c.w) << 16);
        ((uint4*)xb)[idx] = o;
    } else {
        int idx = (b - 4096) * 256 + tid;   // element pair index
        size_t e0 = (size_t)idx * 2;
        const float4* c4 = (const float4*)(coef + e0 * PBASIS);
        float4 a = c4[0], bb = c4[1], c = c4[2], d = c4[3];
        float s0 = (a.x + a.y + a.z + a.w) + (bb.x + bb.y + bb.z + bb.w);
        float s1 = (c.x + c.y + c.z + c.w) + (d.x + d.y + d.z + d.w);
        float2 ww = ((const float2*)w)[idx];
        unsigned b0 = f2bf(s0 * ww.x);
        unsigned b1 = f2bf(s1 * ww.y);
        ((unsigned*)weff)[idx] = b0 | (b1 << 16);
    }
}

// C[m,n] = sum_k A[m,k]*B[n,k]; A=[8192,1024] bf16, B=[1024,1024] bf16, C f32.
// 128x128 tile, BK=64, 4 waves (2x2), wave 4x4 of 16x16x32 MFMA.
// A staged via global_load_lds (16 KB, XOR-swizzled, conflict-free reads).
// B is L2-resident (2 MB total; 256 KB per-XCD working set): fragments are
// loaded straight from global as 16B dwordx4 — halves LDS read BW (the
// K-loop bound) and halves the pre-barrier vmcnt drain volume.
__global__ __launch_bounds__(256, 3) void gemm_bt(
        const unsigned short* __restrict__ A,
        const unsigned short* __restrict__ B,
        float* __restrict__ C) {
    constexpr int K = IN, BK = 64;
    constexpr int ES = 132;                        // epilogue row stride (floats)
    __shared__ __align__(16) char smem[32 * ES * 4];   // 16896 B; staging uses 16 KB
    unsigned short* As = (unsigned short*)smem;    // 128 x 64 bf16 = 16 KB
    float* ebuf = (float*)smem;                    // epilogue reuse

    const int tid  = threadIdx.x;
    const int bm   = blockIdx.x, bn = blockIdx.y;
    const int lane = tid & 63;
    const int wave = tid >> 6;
    const int wm   = wave & 1, wn = wave >> 1;
    const int t    = lane & 15;    // M/N index within 16
    const int q    = lane >> 4;    // K-quad
    const int r8   = t & 7;        // XOR swizzle key

    // ---- A staging addresses: 4 chunks per thread ----
    const char* gA[4];
    void* lA[4];
#pragma unroll
    for (int j = 0; j < 4; ++j) {
        int L = j * 256 + tid;       // 16B-chunk id, 1024 chunks (8 per 64-col row)
        int row = L >> 3;
        int cg  = (L & 7) ^ (row & 7);
        gA[j] = (const char*)(A + ((size_t)(bm * 128 + row)) * K + cg * 8);
        lA[j] = (void*)(As + (size_t)L * 8);
    }

    // ---- A fragment base pointers (LDS) ----
    const unsigned short* aB0 = As + (wm * 64 + t) * BK + ((0 + q) ^ r8) * 8;
    const unsigned short* aB1 = As + (wm * 64 + t) * BK + ((4 + q) ^ r8) * 8;

    // ---- B fragment base pointer (global, row n = bn*128 + wn*64 + i*16 + t) ----
    const unsigned short* gBf = B + ((size_t)(bn * 128 + wn * 64 + t)) * K + q * 8;

    floatx4 acc[4][4];
#pragma unroll
    for (int i = 0; i < 4; ++i)
#pragma unroll
        for (int j = 0; j < 4; ++j)
            acc[i][j] = (floatx4){0.f, 0.f, 0.f, 0.f};

    for (int k0 = 0; k0 < K; k0 += BK) {
        // B fragments for THIS iter: independent of LDS state, issued before
        // the barrier so the vmcnt drain doubles as their completion wait.
        bf16x8 bfv[2][4];
#pragma unroll
        for (int i = 0; i < 4; ++i) {
            const unsigned short* r = gBf + (size_t)i * 16 * K + k0;
            bfv[0][i] = *(const bf16x8*)(r);
            bfv[1][i] = *(const bf16x8*)(r + 32);
        }
#pragma unroll
        for (int j = 0; j < 4; ++j) {
            __builtin_amdgcn_global_load_lds(
                (const __attribute__((address_space(1))) unsigned*)gA[j],
                (__attribute__((address_space(3))) unsigned*)lA[j], 16, 0, 0);
            gA[j] += BK * 2;   // 128 B along K
        }
        __syncthreads();

        bf16x8 af[2][4];
#pragma unroll
        for (int i = 0; i < 4; ++i) {
            af[0][i] = *(const bf16x8*)(aB0 + i * 1024);
            af[1][i] = *(const bf16x8*)(aB1 + i * 1024);
        }
#pragma unroll
        for (int i = 0; i < 4; ++i)
#pragma unroll
            for (int j = 0; j < 4; ++j) {
                acc[i][j] = __builtin_amdgcn_mfma_f32_16x16x32_bf16(
                    af[0][i], bfv[0][j], acc[i][j], 0, 0, 0);
                acc[i][j] = __builtin_amdgcn_mfma_f32_16x16x32_bf16(
                    af[1][i], bfv[1][j], acc[i][j], 0, 0, 0);
            }
        __syncthreads();
    }

    // ---- epilogue: 4 passes of 32 rows through ebuf (16.9 KB) ----
    // D layout: col = t (lane&15), row = q*4 + reg  [m89/m91 verified]
#pragma unroll
    for (int p = 0; p < 4; ++p) {          // block rows [p*32, p*32+32)
        if (p) __syncthreads();            // protect ebuf reuse across passes
        if (wm == (p >> 1)) {
            int dt = p & 1;
#pragma unroll
            for (int half = 0; half < 2; ++half) {
                int tm = dt * 2 + half;
#pragma unroll
                for (int tn = 0; tn < 4; ++tn) {
                    int col = wn * 64 + tn * 16 + t;
#pragma unroll
                    for (int r = 0; r < 4; ++r) {
                        int brow = half * 16 + q * 4 + r;
                        ebuf[brow * ES + col] = acc[tm][tn][r];
                    }
                }
            }
        }
        __syncthreads();
#pragma unroll
        for (int rr = 0; rr < 4; ++rr) {
            int brow = rr * 8 + (tid >> 5);
            int col4 = tid & 31;
            float4 v = *(const float4*)(ebuf + brow * ES + col4 * 4);
            size_t grow = (size_t)(bm * 128 + p * 32 + brow);
            *(float4*)(C + grow * OUTD + bn * 128 + col4 * 4) = v;
        }
    }
}

extern "C" void kernel_launch(void* const* d_in, const int* in_sizes, int n_in,
                              void* d_out, int out_size, void* d_ws, size_t ws_size,
                              hipStream_t stream) {
    const float* x    = (const float*)d_in[0];
    const float* coef = (const float*)d_in[1];
    const float* w    = (const float*)d_in[2];
    float* out = (float*)d_out;

    unsigned short* xb   = (unsigned short*)d_ws;                                   // 16 MB
    unsigned short* weff = (unsigned short*)((char*)d_ws + (size_t)BATCH * IN * 2); // +2 MB

    prep_kernel<<<6144, 256, 0, stream>>>(x, coef, w, xb, weff);
    gemm_bt<<<dim3(BATCH / 128, OUTD / 128), 256, 0, stream>>>(xb, weff, out);
}

// Round 5
// 126.184 us; speedup vs baseline: 1.1468x; 1.1468x over previous
//
#include <hip/hip_runtime.h>
#include <hip/hip_bf16.h>
#include <stdint.h>

#define BATCH 8192
#define IN    1024
#define OUTD  1024
#define PBASIS 8

typedef __attribute__((ext_vector_type(8))) short bf16x8;
typedef __attribute__((ext_vector_type(4))) float floatx4;

__device__ __forceinline__ unsigned short f2bf(float f) {
    union { float f; unsigned u; } v; v.f = f;
    unsigned u = v.u;
    u += 0x7fffu + ((u >> 16) & 1u);   // RNE; inputs finite randn
    return (unsigned short)(u >> 16);
}

// Fused prep: blocks [0,4096) convert x -> bf16 (8 elem/thread);
// blocks [4096,6144) compute w_eff = bf16(sum_p coef * w) (2 elem/thread).
__global__ void prep_kernel(const float* __restrict__ x,
                            const float* __restrict__ coef,
                            const float* __restrict__ w,
                            unsigned short* __restrict__ xb,
                            unsigned short* __restrict__ weff) {
    int b = blockIdx.x;
    int tid = threadIdx.x;
    if (b < 4096) {
        int idx = b * 256 + tid;
        const float4* p = (const float4*)(x + (size_t)idx * 8);
        float4 a = p[0], c = p[1];
        uint4 o;
        o.x = (unsigned)f2bf(a.x) | ((unsigned)f2bf(a.y) << 16);
        o.y = (unsigned)f2bf(a.z) | ((unsigned)f2bf(a.w) << 16);
        o.z = (unsigned)f2bf(c.x) | ((unsigned)f2bf(c.y) << 16);
        o.w = (unsigned)f2bf(c.z) | ((unsigned)f2bf(c.w) << 16);
        ((uint4*)xb)[idx] = o;
    } else {
        int idx = (b - 4096) * 256 + tid;   // element pair index
        size_t e0 = (size_t)idx * 2;
        const float4* c4 = (const float4*)(coef + e0 * PBASIS);
        float4 a = c4[0], bb = c4[1], c = c4[2], d = c4[3];
        float s0 = (a.x + a.y + a.z + a.w) + (bb.x + bb.y + bb.z + bb.w);
        float s1 = (c.x + c.y + c.z + c.w) + (d.x + d.y + d.z + d.w);
        float2 ww = ((const float2*)w)[idx];
        unsigned b0 = f2bf(s0 * ww.x);
        unsigned b1 = f2bf(s1 * ww.y);
        ((unsigned*)weff)[idx] = b0 | (b1 << 16);
    }
}

// C[m,n] = sum_k A[m,k]*B[n,k]; A=[8192,1024], B=[1024,1024] bf16, C f32.
// 128x64 tile -> grid 1024 blocks (4/CU resident: the R4 profile showed the
// 512-block grid capped occupancy at 2/CU and the kernel was latency-bound).
// BK=64, 4 waves (2x2), wave tile 64x32 = acc[4][2], both A and B staged via
// global_load_lds with 3-bit XOR chunk swizzle (conflict-free ds_read_b128).
__global__ __launch_bounds__(256, 4) void gemm_bt(
        const unsigned short* __restrict__ A,
        const unsigned short* __restrict__ B,
        float* __restrict__ C) {
    constexpr int K = IN, BK = 64;
    constexpr int ES = 68;                         // epilogue row stride (floats)
    __shared__ __align__(16) char smem[24576];     // A 16K + B 8K; ebuf 32*68*4=8704
    unsigned short* As = (unsigned short*)smem;    // 128 x 64 bf16
    unsigned short* Bs = As + 128 * BK;            // 64 x 64 bf16
    float* ebuf = (float*)smem;                    // epilogue reuse

    const int tid  = threadIdx.x;
    const int bm   = blockIdx.x, bn = blockIdx.y;
    const int lane = tid & 63;
    const int wave = tid >> 6;
    const int wm   = wave & 1, wn = wave >> 1;
    const int t    = lane & 15;    // M/N index within 16
    const int q    = lane >> 4;    // K-quad
    const int r8   = t & 7;        // XOR swizzle key

    // ---- staging addresses: A 4 chunks/thread, B 2 chunks/thread ----
    const char* gA[4]; void* lA[4];
    const char* gB[2]; void* lB[2];
#pragma unroll
    for (int j = 0; j < 4; ++j) {
        int L = j * 256 + tid;       // A: 1024 16B-chunks, 8 per 64-col row
        int row = L >> 3;
        int cg  = (L & 7) ^ (row & 7);
        gA[j] = (const char*)(A + ((size_t)(bm * 128 + row)) * K + cg * 8);
        lA[j] = (void*)(As + (size_t)L * 8);
    }
#pragma unroll
    for (int j = 0; j < 2; ++j) {
        int L = j * 256 + tid;       // B: 512 chunks
        int row = L >> 3;
        int cg  = (L & 7) ^ (row & 7);
        gB[j] = (const char*)(B + ((size_t)(bn * 64 + row)) * K + cg * 8);
        lB[j] = (void*)(Bs + (size_t)L * 8);
    }

    // ---- fragment base pointers; phys chunk for k-half h, quad q: (h*4+q)^r8 ----
    const unsigned short* aB0 = As + (wm * 64 + t) * BK + ((0 + q) ^ r8) * 8;
    const unsigned short* aB1 = As + (wm * 64 + t) * BK + ((4 + q) ^ r8) * 8;
    const unsigned short* bB0 = Bs + (wn * 32 + t) * BK + ((0 + q) ^ r8) * 8;
    const unsigned short* bB1 = Bs + (wn * 32 + t) * BK + ((4 + q) ^ r8) * 8;

    floatx4 acc[4][2];
#pragma unroll
    for (int i = 0; i < 4; ++i)
#pragma unroll
        for (int j = 0; j < 2; ++j)
            acc[i][j] = (floatx4){0.f, 0.f, 0.f, 0.f};

    for (int k0 = 0; k0 < K; k0 += BK) {
#pragma unroll
        for (int j = 0; j < 4; ++j) {
            __builtin_amdgcn_global_load_lds(
                (const __attribute__((address_space(1))) unsigned*)gA[j],
                (__attribute__((address_space(3))) unsigned*)lA[j], 16, 0, 0);
            gA[j] += BK * 2;
        }
#pragma unroll
        for (int j = 0; j < 2; ++j) {
            __builtin_amdgcn_global_load_lds(
                (const __attribute__((address_space(1))) unsigned*)gB[j],
                (__attribute__((address_space(3))) unsigned*)lB[j], 16, 0, 0);
            gB[j] += BK * 2;
        }
        __syncthreads();

        bf16x8 af[2][4], bfv[2][2];
#pragma unroll
        for (int i = 0; i < 4; ++i) {
            af[0][i] = *(const bf16x8*)(aB0 + i * 1024);
            af[1][i] = *(const bf16x8*)(aB1 + i * 1024);
        }
#pragma unroll
        for (int j = 0; j < 2; ++j) {
            bfv[0][j] = *(const bf16x8*)(bB0 + j * 1024);
            bfv[1][j] = *(const bf16x8*)(bB1 + j * 1024);
        }
#pragma unroll
        for (int i = 0; i < 4; ++i)
#pragma unroll
            for (int j = 0; j < 2; ++j) {
                acc[i][j] = __builtin_amdgcn_mfma_f32_16x16x32_bf16(
                    af[0][i], bfv[0][j], acc[i][j], 0, 0, 0);
                acc[i][j] = __builtin_amdgcn_mfma_f32_16x16x32_bf16(
                    af[1][i], bfv[1][j], acc[i][j], 0, 0, 0);
            }
        __syncthreads();
    }

    // ---- epilogue: 4 passes of 32 rows x 64 cols through ebuf ----
    // D layout: col = t, row = q*4 + reg  [m89/m91 verified]
#pragma unroll
    for (int p = 0; p < 4; ++p) {          // block rows [p*32, p*32+32)
        if (p) __syncthreads();
        if (wm == (p >> 1)) {
            int dt = p & 1;                // tm pair {2dt, 2dt+1}
#pragma unroll
            for (int half = 0; half < 2; ++half) {
                int tm = dt * 2 + half;
#pragma unroll
                for (int tn = 0; tn < 2; ++tn) {
                    int col = wn * 32 + tn * 16 + t;
#pragma unroll
                    for (int r = 0; r < 4; ++r) {
                        int brow = half * 16 + q * 4 + r;
                        ebuf[brow * ES + col] = acc[tm][tn][r];
                    }
                }
            }
        }
        __syncthreads();
#pragma unroll
        for (int rr = 0; rr < 2; ++rr) {
            int brow = rr * 16 + (tid >> 4);
            int col4 = tid & 15;
            float4 v = *(const float4*)(ebuf + brow * ES + col4 * 4);
            size_t grow = (size_t)(bm * 128 + p * 32 + brow);
            *(float4*)(C + grow * OUTD + bn * 64 + col4 * 4) = v;
        }
    }
}

extern "C" void kernel_launch(void* const* d_in, const int* in_sizes, int n_in,
                              void* d_out, int out_size, void* d_ws, size_t ws_size,
                              hipStream_t stream) {
    const float* x    = (const float*)d_in[0];
    const float* coef = (const float*)d_in[1];
    const float* w    = (const float*)d_in[2];
    float* out = (float*)d_out;

    unsigned short* xb   = (unsigned short*)d_ws;                                   // 16 MB
    unsigned short* weff = (unsigned short*)((char*)d_ws + (size_t)BATCH * IN * 2); // +2 MB

    prep_kernel<<<6144, 256, 0, stream>>>(x, coef, w, xb, weff);
    gemm_bt<<<dim3(BATCH / 128, OUTD / 64), 256, 0, stream>>>(xb, weff, out);
}